// Round 18
// baseline (4065.688 us; speedup 1.0000x reference)
//
#include <hip/hip_runtime.h>

#define NBATCH 32
#define NPTS   100000
#define NDIM   6
#define KSEL   1024
#define BPB    8                  // blocks per batch
#define NTHREADS 1024
#define TOTT   (BPB * NTHREADS)   // 8192 threads per batch
#define PPT    13                 // ceil(NPTS / TOTT)
#define MASK51 ((1ull << 51) - 1)

// R17-proven core (3.53 ms): single-leg self-validating two-word exchange
// (13b tag | 51b payload), relaxed SYSTEM scope, wave0-only poll, f32 screen.
// R18: (1) 4-deep pipelined poll (period RTT -> ~RTT/4); (2) speculative
// parallel winner-xyz gather overlapped with the 8-block reduce.
struct Ws {
    unsigned long long w[2][NBATCH][16];   // 8 KB; 16 words = 2 lines per batch/parity
};

__global__ void __launch_bounds__(1024) fps_init(unsigned long long* w) {
    int i = blockIdx.x * blockDim.x + threadIdx.x;
    if (i < (int)(sizeof(Ws) / 8)) w[i] = 0ull;
}

__global__ void __launch_bounds__(NTHREADS, 1) fps_main(const float* __restrict__ pts,
                                                        float* __restrict__ out,
                                                        Ws* __restrict__ ws)
{
#pragma clang fp contract(off)
    const int bid   = blockIdx.x;
    const int batch = bid & (NBATCH - 1);
    const int blk   = bid >> 5;             // 0..7 within batch
    const int tid   = threadIdx.x;
    const int lane  = tid & 63;
    const int wav   = tid >> 6;             // 0..15
    const int tg    = blk * NTHREADS + tid; // 0..8191 within batch

    __shared__ double rdv[16];
    __shared__ int    rii[16];
    __shared__ float  lsh[3];               // broadcast winner xyz
    __shared__ int    idx_l[KSEL];          // leader (blk==0) only
    __shared__ double fr0[16], fr1[16], fr2[16];
    __shared__ double sc[4];

    const float* base = pts + (size_t)batch * NPTS * NDIM;

    // ---- point state in registers; dist in f64 (bit-exact vs numpy f64 FPS).
    float  px[PPT], py[PPT], pz[PPT];
    double pd[PPT];
#pragma unroll
    for (int k = 0; k < PPT; ++k) {
        int gi = k * TOTT + tg;
        if (gi < NPTS) {
            const float* p = base + (size_t)gi * NDIM;
            px[k] = p[0]; py[k] = p[1]; pz[k] = p[2];
            pd[k] = 1e10;
        } else {
            px[k] = 0.f; py[k] = 0.f; pz[k] = 0.f;
            pd[k] = -1.0;   // never wins (valid dists >= 0); screen always skips
        }
    }

    float  lxf = base[0], lyf = base[1], lzf = base[2];
    double lx = (double)lxf, ly = (double)lyf, lz = (double)lzf; // first = idx 0

    for (int t = 0; t < KSEL - 1; ++t) {
        const unsigned long long tag = (unsigned long long)(t + 1);   // <= 1023, fits 13b
        const int par = t & 1;
        // ---- f32 screen + exact f64 update + thread-local argmax (bit-exact: skip
        // only when ddf > pdf*1.0001 which provably implies dd_f64 > pd_f64).
        double bd = -1.0; int bi = 0x7FFFFFFF;
#pragma unroll
        for (int k = 0; k < PPT; ++k) {
            float dxf = px[k] - lxf;
            float dyf = py[k] - lyf;
            float dzf = pz[k] - lzf;
            float ddf = __fmaf_rn(dzf, dzf, __fmaf_rn(dyf, dyf, dxf * dxf));
            double nd = pd[k];
            if (!(ddf > (float)nd * 1.0001f)) {
                double dx = (double)px[k] - lx;
                double dy = (double)py[k] - ly;
                double dz = (double)pz[k] - lz;
                double dd = ((dx * dx) + (dy * dy)) + (dz * dz);
                nd = fmin(nd, dd);
                pd[k] = nd;
            }
            if (nd > bd) { bd = nd; bi = k * TOTT + tg; }  // strict >: first max in-thread
        }
        // ---- wave reduce (dist desc, idx asc)
#pragma unroll
        for (int off = 32; off >= 1; off >>= 1) {
            double od = __shfl_xor(bd, off, 64);
            int    oi = __shfl_xor(bi, off, 64);
            if (od > bd || (od == bd && oi < bi)) { bd = od; bi = oi; }
        }
        if (lane == 0) { rdv[wav] = bd; rii[wav] = bi; }
        __syncthreads();

        if (wav == 0) {
            // ---- block reduce over 16 wave winners (lanes 0..15 hold them)
            double qd = (lane < 16) ? rdv[lane] : -2.0;
            int    qi = (lane < 16) ? rii[lane] : 0x7FFFFFFF;
#pragma unroll
            for (int off = 8; off >= 1; off >>= 1) {
                double od = __shfl_xor(qd, off, 64);
                int    oi = __shfl_xor(qi, off, 64);
                if (od > qd || (od == qd && oi < qi)) { qd = od; qi = oi; }
            }
            // ---- post: lanes 0..1 fire the two self-validating words (no fence)
            unsigned long long db = (unsigned long long)__double_as_longlong(qd); // bit63==0
            unsigned long long w0 = (tag << 51) | (db >> 12);
            unsigned long long w1 = (tag << 51) | ((db & 0xFFFull) << 17)
                                  | (unsigned long long)(unsigned)qi;
            unsigned long long* brow = &ws->w[par][batch][0];
            if (lane < 2)
                __hip_atomic_store(&brow[blk * 2 + lane], (lane == 0) ? w0 : w1,
                                   __ATOMIC_RELAXED, __HIP_MEMORY_SCOPE_SYSTEM);
            // ---- 4-deep pipelined poll: 16 lanes, one word each; check the oldest
            // of 4 in-flight loads (poll period ~RTT/4; self-validating words
            // make stale-but-tagged reads impossible).
            unsigned long long q0 = 0, q1 = 0, q2 = 0, q3 = 0;
            if (lane < 16) {
                q0 = __hip_atomic_load(&brow[lane], __ATOMIC_RELAXED, __HIP_MEMORY_SCOPE_SYSTEM);
                q1 = __hip_atomic_load(&brow[lane], __ATOMIC_RELAXED, __HIP_MEMORY_SCOPE_SYSTEM);
                q2 = __hip_atomic_load(&brow[lane], __ATOMIC_RELAXED, __HIP_MEMORY_SCOPE_SYSTEM);
                q3 = __hip_atomic_load(&brow[lane], __ATOMIC_RELAXED, __HIP_MEMORY_SCOPE_SYSTEM);
            }
            unsigned long long v = q0;
            for (;;) {
                int ok = (lane < 16) ? ((v >> 51) == tag) : 1;
                if (__all(ok)) break;
                unsigned long long qn = 0;
                if (lane < 16)
                    qn = __hip_atomic_load(&brow[lane], __ATOMIC_RELAXED, __HIP_MEMORY_SCOPE_SYSTEM);
                v = q1; q1 = q2; q2 = q3; q3 = qn;
            }
            // ---- assemble per-block records into lanes (block b -> lanes with lane&7 == b)
            unsigned long long p0 = __shfl(v, (lane & 7) * 2,     64) & MASK51;
            unsigned long long p1 = __shfl(v, (lane & 7) * 2 + 1, 64) & MASK51;
            unsigned long long rdb = (p0 << 12) | (p1 >> 17);
            int ridx = (int)(p1 & 0x1FFFFull);
            // ---- speculative gather: lanes 0..7 load their candidate's xyz NOW,
            // overlapping the reduce below (loads in flight during the shuffles).
            float cx = 0.f, cy = 0.f, cz = 0.f;
            if (lane < 8) {
                const float* cp = base + (size_t)ridx * NDIM;   // L2-resident
                cx = cp[0]; cy = cp[1]; cz = cp[2];
            }
            // ---- reduce 8 blocks tracking the winning SLOT (u64 cmp == f64 cmp, nonneg)
            int rslot = lane & 7;
#pragma unroll
            for (int off = 4; off >= 1; off >>= 1) {
                unsigned long long od = __shfl_xor(rdb, off, 64);
                int                oi = __shfl_xor(ridx, off, 64);
                int                os = __shfl_xor(rslot, off, 64);
                if (od > rdb || (od == rdb && oi < ridx)) { rdb = od; ridx = oi; rslot = os; }
            }
            // ---- select winner xyz from the gathering lane (all lanes agree on rslot)
            float wx = __shfl(cx, rslot, 64);
            float wy = __shfl(cy, rslot, 64);
            float wz = __shfl(cz, rslot, 64);
            if (lane == 0) {
                lsh[0] = wx; lsh[1] = wy; lsh[2] = wz;
                if (blk == 0) idx_l[t + 1] = ridx;
            }
        }
        __syncthreads();
        lxf = lsh[0]; lyf = lsh[1]; lzf = lsh[2];
        lx = (double)lxf; ly = (double)lyf; lz = (double)lzf;
    }

    if (blk != 0) return;

    // ============ epilogue (leader block per batch): gather + normalize, f64 accumulation ============
    if (tid == 0) idx_l[0] = 0;
    __syncthreads();

    int si = idx_l[tid];
    const float* sp = base + (size_t)si * NDIM;
    float sx = sp[0], sy = sp[1], szv = sp[2];
    float f3 = sp[3], f4 = sp[4], f5 = sp[5];

    double rx = (double)sx, ry = (double)sy, rz = (double)szv;
#pragma unroll
    for (int off = 32; off >= 1; off >>= 1) {
        rx += __shfl_xor(rx, off, 64);
        ry += __shfl_xor(ry, off, 64);
        rz += __shfl_xor(rz, off, 64);
    }
    if (lane == 0) { fr0[wav] = rx; fr1[wav] = ry; fr2[wav] = rz; }
    __syncthreads();
    if (tid == 0) {
        double tx = 0., ty = 0., tz = 0.;
        for (int i = 0; i < 16; ++i) { tx += fr0[i]; ty += fr1[i]; tz += fr2[i]; }
        sc[0] = tx / (double)KSEL; sc[1] = ty / (double)KSEL; sc[2] = tz / (double)KSEL;
    }
    __syncthreads();
    double ax = (double)sx - sc[0], ay = (double)sy - sc[1], az = (double)szv - sc[2];
    double m = fmax(fabs(ax), fmax(fabs(ay), fabs(az)));
#pragma unroll
    for (int off = 32; off >= 1; off >>= 1) {
        double om = __shfl_xor(m, off, 64);
        m = fmax(m, om);
    }
    if (lane == 0) fr0[wav] = m;
    __syncthreads();
    if (tid == 0) {
        double mm = 0.;
        for (int i = 0; i < 16; ++i) mm = fmax(mm, fr0[i]);
        sc[3] = fmax(mm, 1e-6);
    }
    __syncthreads();
    double scale = sc[3];

    float* ob = out + ((size_t)batch * KSEL + tid) * NDIM;
    ob[0] = (float)(ax / scale);
    ob[1] = (float)(ay / scale);
    ob[2] = (float)(az / scale);
    ob[3] = f3; ob[4] = f4; ob[5] = f5;
}

extern "C" void kernel_launch(void* const* d_in, const int* in_sizes, int n_in,
                              void* d_out, int out_size, void* d_ws, size_t ws_size,
                              hipStream_t stream)
{
    const float* pts = (const float*)d_in[0];
    float* out = (float*)d_out;
    Ws* ws = (Ws*)d_ws;

    // re-zero slot words every call (graph replays must not see stale tags)
    hipLaunchKernelGGL(fps_init, dim3(1), dim3(1024), 0, stream, (unsigned long long*)d_ws);

    void* args[] = { (void*)&pts, (void*)&out, (void*)&ws };
    hipLaunchCooperativeKernel((void*)fps_main, dim3(NBATCH * BPB), dim3(NTHREADS),
                               args, 0, stream);
}